// Round 6
// baseline (214.979 us; speedup 1.0000x reference)
//
#include <hip/hip_runtime.h>
#include <hip/hip_fp16.h>

// MultiScaleRoIAlign (round 6).
// Pass 1 (repack v3): [B,C,H,W] fp32 -> ws [B, hw, C] fp16.
//   Block = 256ch x 128hw tile, fp16 LDS (64 KB) with XOR-swizzled dwords.
//   Reads: 512 B contiguous per wave-instr. Writes: full 512 B ws rows,
//   128 consecutive rows/block => 64 KB contiguous write stream.
// Pass 2 (main, round-4 version verbatim): block = roi, lane owns 4 channels,
//   each bilinear corner = one coalesced 8 B load; [c][bin] LDS staging for
//   float4-coalesced output writes.

#define ROI_OUT 7
#define NSAMP   14
#define C_TOT   256
#define N_PER_B 256
#define BINS    49
#define TOT_HW  53125          // 40000 + 10000 + 2500 + 625 per image
#define TILE_HW 128
#define NTILE_X 417            // 313 + 79 + 20 + 5 hw-tiles of 128

// ---------------- pass 1: transpose to channels-last fp16 ----------------
__global__ __launch_bounds__(256)
void repack_kernel(const float* __restrict__ f0, const float* __restrict__ f1,
                   const float* __restrict__ f2, const float* __restrict__ f3,
                   __half* __restrict__ ws)
{
    // dword-indexed tile: entry [c*64 + (pair ^ (c&31))] holds channel c,
    // hw-pair `pair` (low half = even hw, high half = odd hw). 65536 B.
    __shared__ __half2 tile[C_TOT * 64];

    const int tx = blockIdx.x;
    const float* feat; int HW, base, hw0;
    if (tx < 313)      { feat = f0; HW = 40000; base = 0;     hw0 = tx * TILE_HW; }
    else if (tx < 392) { feat = f1; HW = 10000; base = 40000; hw0 = (tx - 313) * TILE_HW; }
    else if (tx < 412) { feat = f2; HW = 2500;  base = 50000; hw0 = (tx - 392) * TILE_HW; }
    else               { feat = f3; HW = 625;   base = 52500; hw0 = (tx - 412) * TILE_HW; }

    const int b   = blockIdx.y;
    const int tid = threadIdx.x;
    const int w   = tid >> 6;            // wave 0..3
    const int l   = tid & 63;            // lane

    const float* src = feat + (size_t)b * ((size_t)C_TOT * HW);

    // level-3 planes are only 4B-aligned (625*4 B stride) -> scalar path there
    const bool vec = (hw0 + TILE_HW <= HW) && (HW != 625);

    // ---- phase A: stage tile (wave covers one channel-row per instr) ----
    if (vec) {
        #pragma unroll 8
        for (int c = w; c < C_TOT; c += 4) {
            const float2 v = *(const float2*)(src + (size_t)c * HW + hw0 + 2 * l);
            tile[c * 64 + (l ^ (c & 31))] = __floats2half2_rn(v.x, v.y);
        }
    } else {
        #pragma unroll 4
        for (int c = w; c < C_TOT; c += 4) {
            const int h0 = hw0 + 2 * l;
            const float a0 = (h0 < HW)     ? src[(size_t)c * HW + h0]     : 0.0f;
            const float a1 = (h0 + 1 < HW) ? src[(size_t)c * HW + h0 + 1] : 0.0f;
            tile[c * 64 + (l ^ (c & 31))] = __floats2half2_rn(a0, a1);
        }
    }
    __syncthreads();

    // ---- phase B: write full 512 B rows; block emits 64 KB contiguous ----
    __half* dstb = ws + ((size_t)b * TOT_HW + base) * C_TOT;
    const int k = l & 31;                // channel group (8 ch each)
    const int p = l >> 5;                // 0..1
    #pragma unroll
    for (int j = 0; j < 8; ++j) {
        const int P    = j * 8 + w * 2 + p;     // hw-pair 0..63
        const int row0 = hw0 + 2 * P;
        uint e[4], o[4];
        #pragma unroll
        for (int ii = 0; ii < 4; ++ii) {
            const int c0 = 8 * k + 2 * ii;
            const int c1 = c0 + 1;
            const __half2 r0 = tile[c0 * 64 + (P ^ (c0 & 31))];
            const __half2 r1 = tile[c1 * 64 + (P ^ (c1 & 31))];
            e[ii] = (uint)__half_as_ushort(r0.x) | ((uint)__half_as_ushort(r1.x) << 16);
            o[ii] = (uint)__half_as_ushort(r0.y) | ((uint)__half_as_ushort(r1.y) << 16);
        }
        if (row0 < HW)
            *(uint4*)(dstb + (size_t)row0 * C_TOT + 8 * k) = make_uint4(e[0], e[1], e[2], e[3]);
        if (row0 + 1 < HW)
            *(uint4*)(dstb + (size_t)(row0 + 1) * C_TOT + 8 * k) = make_uint4(o[0], o[1], o[2], o[3]);
    }
}

// ---------------- pass 2: per-roi pooled gather (round-4 version) ----------------
__global__ __launch_bounds__(256)
void msroi_main(const __half* __restrict__ ws, const float* __restrict__ boxes,
                float* __restrict__ out)
{
    __shared__ float oacc[C_TOT * BINS];   // [c][bin], 50176 B
    __shared__ int4  pY[NSAMP], pX[NSAMP];

    const int tid = threadIdx.x;
    const int roi = blockIdx.x;
    const int b   = roi >> 8;

    const float* bxp = boxes + (size_t)roi * 4;
    float bx1 = bxp[0], by1 = bxp[1], bx2 = bxp[2], by2 = bxp[3];
    float area = (bx2 - bx1) * (by2 - by1);
    float s    = sqrtf(area);
    float lvlf = floorf(4.0f + log2f(s * (1.0f / 224.0f)) + 1e-6f);
    lvlf = fminf(fmaxf(lvlf, 2.0f), 5.0f);
    int level = (int)lvlf - 2;

    int H, W, lvbase; float scale;
    switch (level) {
        case 0:  H = 200; W = 200; lvbase = 0;     scale = 0.25f;    break;
        case 1:  H = 100; W = 100; lvbase = 40000; scale = 0.125f;   break;
        case 2:  H = 50;  W = 50;  lvbase = 50000; scale = 0.0625f;  break;
        default: H = 25;  W = 25;  lvbase = 52500; scale = 0.03125f; break;
    }

    float x1 = bx1 * scale, y1 = by1 * scale;
    float roi_w = fmaxf(bx2 * scale - x1, 1.0f);
    float roi_h = fmaxf(by2 * scale - y1, 1.0f);
    float bin_w = roi_w * (1.0f / ROI_OUT);
    float bin_h = roi_h * (1.0f / ROI_OUT);

    if (tid < 2 * NSAMP) {
        bool isy = tid >= NSAMP;
        int  j   = isy ? tid - NSAMP : tid;
        int  pb  = j >> 1, sub = j & 1;
        float start = isy ? y1 : x1;
        float bsz   = isy ? bin_h : bin_w;
        int   lim   = isy ? H : W;
        float ss = start + (float)pb * bsz + ((float)sub + 0.5f) * bsz * 0.5f;
        float v  = (ss >= -1.0f && ss <= (float)lim) ? 1.0f : 0.0f;
        float cc = fminf(fmaxf(ss, 0.0f), (float)lim - 1.0f);
        int   i0 = (int)floorf(cc);
        int   i1 = min(i0 + 1, lim - 1);
        float lf = cc - (float)i0;
        int4 pk; pk.x = i0; pk.y = i1;
        pk.z = __float_as_int(lf); pk.w = __float_as_int(v);
        if (isy) pY[j] = pk; else pX[j] = pk;
    }
    __syncthreads();

    const int wave = tid >> 6;
    const int lane = tid & 63;
    const int c    = lane * 4;
    const __half* bas = ws + ((size_t)b * TOT_HW + lvbase) * C_TOT + c;

    for (int bin = wave; bin < BINS; bin += 4) {
        int ph = bin / ROI_OUT;
        int pw = bin - ph * ROI_OUT;
        float a0 = 0.f, a1 = 0.f, a2 = 0.f, a3 = 0.f;

        #pragma unroll
        for (int sy = 0; sy < 2; ++sy) {
            int4 py  = pY[2 * ph + sy];
            float ly = __int_as_float(py.z);
            float vy = __int_as_float(py.w);
            float hy = 1.0f - ly;
            #pragma unroll
            for (int sx = 0; sx < 2; ++sx) {
                int4 px  = pX[2 * pw + sx];
                float lx = __int_as_float(px.z);
                float vv = vy * __int_as_float(px.w);
                float hx = 1.0f - lx;
                float w00 = vv * hy * hx, w01 = vv * hy * lx;
                float w10 = vv * ly * hx, w11 = vv * ly * lx;

                int2 r00 = *(const int2*)(bas + (size_t)(py.x * W + px.x) * C_TOT);
                int2 r01 = *(const int2*)(bas + (size_t)(py.x * W + px.y) * C_TOT);
                int2 r10 = *(const int2*)(bas + (size_t)(py.y * W + px.x) * C_TOT);
                int2 r11 = *(const int2*)(bas + (size_t)(py.y * W + px.y) * C_TOT);

                float2 g0, g1;
                g0 = __half22float2(*(__half2*)&r00.x); g1 = __half22float2(*(__half2*)&r00.y);
                a0 += w00 * g0.x; a1 += w00 * g0.y; a2 += w00 * g1.x; a3 += w00 * g1.y;
                g0 = __half22float2(*(__half2*)&r01.x); g1 = __half22float2(*(__half2*)&r01.y);
                a0 += w01 * g0.x; a1 += w01 * g0.y; a2 += w01 * g1.x; a3 += w01 * g1.y;
                g0 = __half22float2(*(__half2*)&r10.x); g1 = __half22float2(*(__half2*)&r10.y);
                a0 += w10 * g0.x; a1 += w10 * g0.y; a2 += w10 * g1.x; a3 += w10 * g1.y;
                g0 = __half22float2(*(__half2*)&r11.x); g1 = __half22float2(*(__half2*)&r11.y);
                a0 += w11 * g0.x; a1 += w11 * g0.y; a2 += w11 * g1.x; a3 += w11 * g1.y;
            }
        }
        oacc[(c + 0) * BINS + bin] = a0 * 0.25f;
        oacc[(c + 1) * BINS + bin] = a1 * 0.25f;
        oacc[(c + 2) * BINS + bin] = a2 * 0.25f;
        oacc[(c + 3) * BINS + bin] = a3 * 0.25f;
    }
    __syncthreads();

    float4*       o4 = (float4*)(out + (size_t)roi * (C_TOT * BINS));
    const float4* s4 = (const float4*)oacc;
    for (int j = tid; j < (C_TOT * BINS) / 4; j += 256) o4[j] = s4[j];
}

// ---------------- fallback: direct gather (ws too small) ----------------
__global__ __launch_bounds__(256)
void msroi_direct(const float* __restrict__ f0, const float* __restrict__ f1,
                  const float* __restrict__ f2, const float* __restrict__ f3,
                  const float* __restrict__ boxes, float* __restrict__ out, int total)
{
    int e = blockIdx.x * 256 + threadIdx.x;
    if (e >= total) return;
    int bin = e % BINS;
    int c   = (e / BINS) % C_TOT;
    int roi = e / (BINS * C_TOT);
    int b   = roi / N_PER_B;

    const float* bx = boxes + (size_t)roi * 4;
    float bx1 = bx[0], by1 = bx[1], bx2 = bx[2], by2 = bx[3];
    float area = (bx2 - bx1) * (by2 - by1);
    float s    = sqrtf(area);
    float lvlf = floorf(4.0f + log2f(s * (1.0f / 224.0f)) + 1e-6f);
    lvlf = fminf(fmaxf(lvlf, 2.0f), 5.0f);
    int level = (int)lvlf - 2;

    const float* feat; int H, W; float scale;
    switch (level) {
        case 0:  feat = f0; H = 200; W = 200; scale = 0.25f;    break;
        case 1:  feat = f1; H = 100; W = 100; scale = 0.125f;   break;
        case 2:  feat = f2; H = 50;  W = 50;  scale = 0.0625f;  break;
        default: feat = f3; H = 25;  W = 25;  scale = 0.03125f; break;
    }
    float x1 = bx1 * scale, y1 = by1 * scale;
    float roi_w = fmaxf(bx2 * scale - x1, 1.0f);
    float roi_h = fmaxf(by2 * scale - y1, 1.0f);
    float bin_w = roi_w * (1.0f / ROI_OUT);
    float bin_h = roi_h * (1.0f / ROI_OUT);
    int ph = bin / ROI_OUT, pw = bin - ph * ROI_OUT;
    const float* plane = feat + ((size_t)(b * C_TOT + c)) * (size_t)(H * W);
    float Hf = (float)H, Wf = (float)W, acc = 0.0f;
    #pragma unroll
    for (int sy = 0; sy < 2; ++sy) {
        float ys = y1 + (float)ph * bin_h + ((float)sy + 0.5f) * bin_h * 0.5f;
        float vy = (ys >= -1.0f && ys <= Hf) ? 1.0f : 0.0f;
        float y  = fminf(fmaxf(ys, 0.0f), Hf - 1.0f);
        int   y0 = (int)floorf(y);
        int   y1i = min(y0 + 1, H - 1);
        float ly = y - (float)y0, hy = 1.0f - ly;
        int ro0 = y0 * W, ro1 = y1i * W;
        #pragma unroll
        for (int sx = 0; sx < 2; ++sx) {
            float xs = x1 + (float)pw * bin_w + ((float)sx + 0.5f) * bin_w * 0.5f;
            float vx = (xs >= -1.0f && xs <= Wf) ? 1.0f : 0.0f;
            float x  = fminf(fmaxf(xs, 0.0f), Wf - 1.0f);
            int   x0 = (int)floorf(x);
            int   x1i = min(x0 + 1, W - 1);
            float lx = x - (float)x0, hx = 1.0f - lx;
            float v00 = plane[ro0 + x0],  v01 = plane[ro0 + x1i];
            float v10 = plane[ro1 + x0],  v11 = plane[ro1 + x1i];
            acc += vy * vx * (hy * (hx * v00 + lx * v01) + ly * (hx * v10 + lx * v11));
        }
    }
    out[e] = acc * 0.25f;
}

extern "C" void kernel_launch(void* const* d_in, const int* in_sizes, int n_in,
                              void* d_out, int out_size, void* d_ws, size_t ws_size,
                              hipStream_t stream)
{
    const float* f0    = (const float*)d_in[0];
    const float* f1    = (const float*)d_in[1];
    const float* f2    = (const float*)d_in[2];
    const float* f3    = (const float*)d_in[3];
    const float* boxes = (const float*)d_in[4];
    float* out = (float*)d_out;

    const size_t ws_needed = (size_t)2 * TOT_HW * C_TOT * sizeof(__half); // 54.4 MB
    if (ws_size >= ws_needed) {
        __half* ws = (__half*)d_ws;
        hipLaunchKernelGGL(repack_kernel, dim3(NTILE_X, 2), dim3(256), 0, stream,
                           f0, f1, f2, f3, ws);
        hipLaunchKernelGGL(msroi_main, dim3(2 * N_PER_B), dim3(256), 0, stream,
                           ws, boxes, out);
    } else {
        int total = out_size;
        hipLaunchKernelGGL(msroi_direct, dim3((total + 255) / 256), dim3(256), 0, stream,
                           f0, f1, f2, f3, boxes, out, total);
    }
}